// Round 10
// baseline (704.245 us; speedup 1.0000x reference)
//
#include <hip/hip_runtime.h>
#include <hip/hip_bf16.h>
#include <hip/hip_fp8.h>
#include <math.h>
#include <stdint.h>
#include <stddef.h>

// ---------------------------------------------------------------------------
// MetaEvidentialGSL: N=8192, D=768, H1=512, H2=256
// R2: XOR swizzle -> 0 conflicts. R4: dbuf + raw vmcnt barrier. R5: XCD
// remap. R6: head2 plain bf16. R7: fp8 attention. R8: fused-Y PV.
// R9: scores 2xN=4096 (L2-resident B), PV 64x64 (6 blk/CU).
// R10: fp8 GEMMs load the A fragment global->VGPR directly (A has no
//      cross-wave reuse; LDS staging of A bought nothing). Halves the
//      ds_read_b128 stream that the R9 counters showed as the binding pipe
//      (scores 8->4, PV 4->2 reads/wave-iter). B stays LDS-staged (shared
//      by all 4 waves). 2-phase unrolled K-loop ping-pongs A register sets
//      so no cross-iter register copies.
// ---------------------------------------------------------------------------

#define NT    8192
#define DD    768
#define DH1   512
#define DH2   256
#define SPAN  4096   // scores N-split

typedef __attribute__((ext_vector_type(8))) short  short8;
typedef __attribute__((ext_vector_type(4))) float  f32x4;
typedef __attribute__((ext_vector_type(2))) long   longx2;

#define MFMA16(a, b, c) __builtin_amdgcn_mfma_f32_16x16x32_bf16((a), (b), (c), 0, 0, 0)
#define MFMAF8(a, b, c) __builtin_amdgcn_mfma_f32_16x16x32_fp8_fp8((a), (b), (c), 0, 0, 0)

__device__ __forceinline__ float bf2f(__hip_bfloat16 x) { return __bfloat162float(x); }
__device__ __forceinline__ __hip_bfloat16 f2bf(float x) { return __float2bfloat16(x); }
__device__ __forceinline__ uint8_t f2fp8(float x) { return __hip_fp8_e4m3(x).__x; }

__device__ __forceinline__ float gelu_f(float x) {
    return 0.5f * x * (1.0f + erff(x * 0.7071067811865476f));
}
__device__ __forceinline__ float softplus_f(float x) {
    return (x > 20.0f) ? x : log1pf(expf(x));
}

// async 16B/lane global->LDS. LDS dest must be wave-uniform base + lane*16.
__device__ __forceinline__ void gload16(const void* g, void* l) {
    __builtin_amdgcn_global_load_lds(
        (const __attribute__((address_space(1))) void*)g,
        (__attribute__((address_space(3))) void*)l, 16, 0, 0);
}

// wait until <=N vm ops outstanding, then barrier.
template <int N>
__device__ __forceinline__ void wait_barrier() {
    asm volatile("s_waitcnt vmcnt(%0)\n\ts_barrier" :: "i"(N) : "memory");
}
__device__ __forceinline__ void plain_barrier() {
    asm volatile("s_barrier" ::: "memory");
}

// XCD-aware remap: linear workgroup id round-robins across 8 XCDs (id % 8).
__device__ __forceinline__ void xcd_remap(int& bx, int& by) {
    const int nbx = gridDim.x, nby = gridDim.y;
    if ((nby & 7) == 0) {
        const int lin = by * nbx + bx;
        const int x   = lin & 7;
        const int s   = lin >> 3;
        bx = s % nbx;
        by = x + 8 * (s / nbx);
    }
}

// ---------------------------------------------------------------------------
// bf16 GEMM (heads + QKV): C(MxN) = A @ Bt^T. BK=32, double-buffered.
// EPI: 0 = store bf16 (obf_hi) and/or fp8 (of8); 1 = bias+gelu -> bf16 (+lo)
// ---------------------------------------------------------------------------
template <int EPI, bool SPLIT, int TM, int TN>
__global__ __launch_bounds__(256)
void gemm_bt(const __hip_bfloat16* __restrict__ Ahi, const __hip_bfloat16* __restrict__ Alo, int lda,
             const __hip_bfloat16* __restrict__ Bhi, const __hip_bfloat16* __restrict__ Blo, int ldb,
             __hip_bfloat16* __restrict__ obf_hi, __hip_bfloat16* __restrict__ obf_lo,
             uint8_t* __restrict__ of8, int ldc,
             const float* __restrict__ bias, int K)
{
    constexpr int NB  = SPLIT ? 2 : 1;
    constexpr int WRM = (TM == 128 && TN == 128) ? 2 : (TM == 128 ? 4 : 2);
    constexpr int WCN = 4 / WRM;
    constexpr int WTM = TM / WRM;
    constexpr int WTN = TN / WCN;
    constexpr int MI  = WTM / 16;
    constexpr int NI  = WTN / 16;
    constexpr int PA  = TM / 64;
    constexpr int PB  = TN / 64;
    constexpr int LPI = (PA + PB) * NB;

    __shared__ __align__(16) __hip_bfloat16 As[NB][2][TM * 32];
    __shared__ __align__(16) __hip_bfloat16 Bs[NB][2][TN * 32];

    const int tid  = threadIdx.x;
    const int wave = tid >> 6;
    const int lane = tid & 63;
    int bx = blockIdx.x, by = blockIdx.y;
    xcd_remap(bx, by);
    const int tm = by * TM;
    const int tn = bx * TN;

    const int srow  = tid >> 2;
    const int sgcol = ((tid & 3) ^ ((srow >> 1) & 3)) * 8;
    const int lofs  = srow * 32 + (tid & 3) * 8;

    size_t aoffs[PA], boffs[PB];
#pragma unroll
    for (int p = 0; p < PA; ++p) aoffs[p] = (size_t)(tm + p * 64 + srow) * lda + sgcol;
#pragma unroll
    for (int p = 0; p < PB; ++p) boffs[p] = (size_t)(tn + p * 64 + srow) * ldb + sgcol;

    auto stage = [&](int k0, int buf) {
#pragma unroll
        for (int p = 0; p < PA; ++p)
            gload16(Ahi + aoffs[p] + k0, &As[0][buf][p * 2048 + lofs]);
#pragma unroll
        for (int p = 0; p < PB; ++p)
            gload16(Bhi + boffs[p] + k0, &Bs[0][buf][p * 2048 + lofs]);
        if constexpr (SPLIT) {
#pragma unroll
            for (int p = 0; p < PA; ++p)
                gload16(Alo + aoffs[p] + k0, &As[1][buf][p * 2048 + lofs]);
#pragma unroll
            for (int p = 0; p < PB; ++p)
                gload16(Blo + boffs[p] + k0, &Bs[1][buf][p * 2048 + lofs]);
        }
    };

    f32x4 acc[MI][NI];
#pragma unroll
    for (int i = 0; i < MI; ++i)
#pragma unroll
        for (int j = 0; j < NI; ++j) {
            f32x4 z = {0.0f, 0.0f, 0.0f, 0.0f};
            acc[i][j] = z;
        }

    const int wm   = (wave / WCN) * WTM;
    const int wn   = (wave % WCN) * WTN;
    const int l16  = lane & 15;
    const int quad = lane >> 4;
    const int rchunk = (quad ^ ((l16 >> 1) & 3)) * 8;
    const int arow0  = (wm + l16) * 32 + rchunk;
    const int brow0  = (wn + l16) * 32 + rchunk;

    const int nIter = K >> 5;
    stage(0, 0);
    for (int k = 0; k < nIter; ++k) {
        const int cb = k & 1;
        if (k + 1 < nIter) {
            stage((k + 1) << 5, cb ^ 1);
            wait_barrier<LPI>();
        } else {
            wait_barrier<0>();
        }

        short8 ah[MI], bh[NI];
#pragma unroll
        for (int i = 0; i < MI; ++i) ah[i] = *(const short8*)&As[0][cb][arow0 + i * 512];
#pragma unroll
        for (int j = 0; j < NI; ++j) bh[j] = *(const short8*)&Bs[0][cb][brow0 + j * 512];
        if constexpr (SPLIT) {
            short8 al[MI], bl[NI];
#pragma unroll
            for (int i = 0; i < MI; ++i) al[i] = *(const short8*)&As[1][cb][arow0 + i * 512];
#pragma unroll
            for (int j = 0; j < NI; ++j) bl[j] = *(const short8*)&Bs[1][cb][brow0 + j * 512];
#pragma unroll
            for (int mi = 0; mi < MI; ++mi)
#pragma unroll
                for (int ni = 0; ni < NI; ++ni) {
                    acc[mi][ni] = MFMA16(ah[mi], bh[ni], acc[mi][ni]);
                    acc[mi][ni] = MFMA16(ah[mi], bl[ni], acc[mi][ni]);
                    acc[mi][ni] = MFMA16(al[mi], bh[ni], acc[mi][ni]);
                }
        } else {
#pragma unroll
            for (int mi = 0; mi < MI; ++mi)
#pragma unroll
                for (int ni = 0; ni < NI; ++ni)
                    acc[mi][ni] = MFMA16(ah[mi], bh[ni], acc[mi][ni]);
        }
        plain_barrier();
    }

    // C/D layout: col = lane&15, row = (lane>>4)*4 + reg  [verified m89/m91]
    const int rbase = tm + wm + quad * 4;
    const int cbase = tn + wn + l16;

    if constexpr (EPI == 0) {
#pragma unroll
        for (int mi = 0; mi < MI; ++mi)
#pragma unroll
            for (int ni = 0; ni < NI; ++ni) {
                f32x4 v = acc[mi][ni];
                const int col = cbase + ni * 16;
#pragma unroll
                for (int r = 0; r < 4; ++r) {
                    size_t idx = (size_t)(rbase + mi * 16 + r) * ldc + col;
                    if (obf_hi) obf_hi[idx] = f2bf(v[r]);
                    if (of8)    of8[idx]    = f2fp8(v[r]);
                }
            }
    } else {  // EPI == 1
#pragma unroll
        for (int mi = 0; mi < MI; ++mi)
#pragma unroll
            for (int ni = 0; ni < NI; ++ni) {
                f32x4 v = acc[mi][ni];
                const int col = cbase + ni * 16;
                const float b = bias[col];
#pragma unroll
                for (int r = 0; r < 4; ++r) {
                    float g = gelu_f(v[r] + b);
                    __hip_bfloat16 h = f2bf(g);
                    size_t idx = (size_t)(rbase + mi * 16 + r) * ldc + col;
                    obf_hi[idx] = h;
                    if (obf_lo) obf_lo[idx] = f2bf(g - bf2f(h));
                }
            }
    }
}

// ---------------------------------------------------------------------------
// fp8 GEMM (attention): C(MxN) = A(MxK) @ Bt(NxK)^T, fp8 e4m3 inputs.
// BK=64. A fragments: direct global->VGPR (no cross-wave reuse; wave's A
// load touches 16 rows x full 64B lines -> line-efficient, L2-served).
// B: LDS-staged (shared by 4 waves), double-buffered, XOR chunk swizzle.
// A k-order = quad*16 bytes, matching B's unswizzled k-permutation (dot
// products are k-permutation invariant when applied to both operands).
// 2-phase unrolled K-loop ping-pongs A register sets (no copies).
// EPI: 2 = w=exp(acc/sqrt(D))*G[col] -> fp8, atomic rowsum E (exp) / T (w)
//      4 = fused Y epilogue: Y = X + gelu(alpha*acc + bg),
//          alpha = G/(E*max(G*T/E,1e-8))   (exact reference clamp semantics)
// ---------------------------------------------------------------------------
template <int EPI, int TM, int TN>
__global__ __launch_bounds__(256)
void gemm_f8(const uint8_t* __restrict__ A, int lda,
             const uint8_t* __restrict__ B, int ldb,
             uint8_t* __restrict__ of8, int ldc,
             const float* __restrict__ Gv, float* __restrict__ Esum,
             float* __restrict__ Tsum,
             const float* __restrict__ Xf, const float* __restrict__ bg2,
             const float* __restrict__ Grow, const float* __restrict__ Erow,
             const float* __restrict__ Trow,
             __hip_bfloat16* __restrict__ Yout, int K)
{
    constexpr int WRM = (TM == 128 && TN == 128) ? 2 : (TM == 128 ? 4 : 2);
    constexpr int WCN = 4 / WRM;
    constexpr int WTM = TM / WRM;
    constexpr int WTN = TN / WCN;
    constexpr int MI  = WTM / 16;
    constexpr int NI  = WTN / 16;
    constexpr int PB  = TN / 64;
    constexpr int LPI = PB + MI;   // outstanding after issuing next-iter loads

    __shared__ __align__(16) uint8_t Bs[2][TN * 64];

    const int tid  = threadIdx.x;
    const int wave = tid >> 6;
    const int lane = tid & 63;
    int bx = blockIdx.x, by = blockIdx.y;
    xcd_remap(bx, by);
    const int tm = by * TM;
    const int tn = bx * TN;

    const int srow  = tid >> 2;
    const int sgcol = ((tid & 3) ^ ((srow >> 1) & 3)) * 16;   // byte col
    const int lofs  = tid * 16;

    size_t boffs[PB];
#pragma unroll
    for (int p = 0; p < PB; ++p) boffs[p] = (size_t)(tn + p * 64 + srow) * ldb + sgcol;

    auto stageB = [&](int k0, int buf) {
#pragma unroll
        for (int p = 0; p < PB; ++p)
            gload16(B + boffs[p] + k0, &Bs[buf][p * 4096 + lofs]);
    };

    f32x4 acc[MI][NI];
#pragma unroll
    for (int i = 0; i < MI; ++i)
#pragma unroll
        for (int j = 0; j < NI; ++j) {
            f32x4 z = {0.0f, 0.0f, 0.0f, 0.0f};
            acc[i][j] = z;
        }

    const int wm   = (wave / WCN) * WTM;
    const int wn   = (wave % WCN) * WTN;
    const int l16  = lane & 15;
    const int quad = lane >> 4;
    const int rchunk = (quad ^ ((l16 >> 1) & 3)) * 16;
    const int brow0  = (wn + l16) * 64 + rchunk;

    // A row pointers: lane reads global k-bytes [k0 + quad*16, +16) of its row
    const uint8_t* ap[MI];
#pragma unroll
    for (int i = 0; i < MI; ++i)
        ap[i] = A + (size_t)(tm + wm + i * 16 + l16) * lda + quad * 16;

    longx2 a0[MI], a1[MI];
    auto loadA = [&](longx2* dst, int kIter) {
#pragma unroll
        for (int i = 0; i < MI; ++i)
            dst[i] = *(const longx2*)(ap[i] + (size_t)kIter * 64);
    };
    auto compute = [&](const longx2* a, int buf) {
        longx2 b[NI];
#pragma unroll
        for (int j = 0; j < NI; ++j) b[j] = *(const longx2*)&Bs[buf][brow0 + j * 1024];
#pragma unroll
        for (int mi = 0; mi < MI; ++mi)
#pragma unroll
            for (int ni = 0; ni < NI; ++ni) {
                acc[mi][ni] = MFMAF8(a[mi][0], b[ni][0], acc[mi][ni]);
                acc[mi][ni] = MFMAF8(a[mi][1], b[ni][1], acc[mi][ni]);
            }
    };

    const int nIter = K >> 6;   // always even here (12 or 128)
    stageB(0, 0);
    loadA(a0, 0);
    for (int k = 0; k < nIter; k += 2) {
        // phase 0: consume buf0/a0, prefetch k+1 into buf1/a1
        if (k + 1 < nIter) {
            stageB((k + 1) << 6, 1);
            loadA(a1, k + 1);
            wait_barrier<LPI>();
        } else {
            wait_barrier<0>();
        }
        compute(a0, 0);
        plain_barrier();
        // phase 1: consume buf1/a1, prefetch k+2 into buf0/a0
        if (k + 1 < nIter) {
            if (k + 2 < nIter) {
                stageB((k + 2) << 6, 0);
                loadA(a0, k + 2);
                wait_barrier<LPI>();
            } else {
                wait_barrier<0>();
            }
            compute(a1, 1);
            plain_barrier();
        }
    }

    const int rbase = tm + wm + quad * 4;
    const int cbase = tn + wn + l16;

    if constexpr (EPI == 2) {
        const float SCL = 0.03608439182435161f;   // 1/sqrt(768)
#pragma unroll
        for (int mi = 0; mi < MI; ++mi) {
            float sE[4] = {0.f, 0.f, 0.f, 0.f};
            float sT[4] = {0.f, 0.f, 0.f, 0.f};
#pragma unroll
            for (int ni = 0; ni < NI; ++ni) {
                f32x4 v = acc[mi][ni];
                const int col = cbase + ni * 16;
                const float g = Gv[col];
#pragma unroll
                for (int r = 0; r < 4; ++r) {
                    float we = __expf(v[r] * SCL);
                    float w  = we * g;
                    of8[(size_t)(rbase + mi * 16 + r) * ldc + col] = f2fp8(w);
                    sE[r] += we;
                    sT[r] += w;
                }
            }
#pragma unroll
            for (int st = 1; st < 16; st <<= 1)
#pragma unroll
                for (int r = 0; r < 4; ++r) {
                    sE[r] += __shfl_xor(sE[r], st);
                    sT[r] += __shfl_xor(sT[r], st);
                }
            if (l16 == 0) {
#pragma unroll
                for (int r = 0; r < 4; ++r) {
                    atomicAdd(&Esum[rbase + mi * 16 + r], sE[r]);
                    atomicAdd(&Tsum[rbase + mi * 16 + r], sT[r]);
                }
            }
        }
    } else {  // EPI == 4: fused Y = X + gelu(alpha*acc + bg)
#pragma unroll
        for (int mi = 0; mi < MI; ++mi) {
#pragma unroll
            for (int r = 0; r < 4; ++r) {
                const int row = rbase + mi * 16 + r;
                const float g = Grow[row], e = Erow[row], t = Trow[row];
                const float denom = fmaxf(g * t / e, 1e-8f);
                const float alpha = g / (e * denom);
#pragma unroll
                for (int ni = 0; ni < NI; ++ni) {
                    const int col = cbase + ni * 16;
                    const float m = alpha * acc[mi][ni][r];
                    const size_t idx = (size_t)row * ldc + col;
                    Yout[idx] = f2bf(Xf[idx] + gelu_f(m + bg2[col]));
                }
            }
        }
    }
}

// ---------------------------------------------------------------------------
__global__ __launch_bounds__(256)
void transpose_f2b(const float* __restrict__ in, int ldin,
                   __hip_bfloat16* __restrict__ ohi, __hip_bfloat16* __restrict__ olo, int ldout)
{
    __shared__ float t[32][33];
    const int tx = threadIdx.x & 31;
    const int ty = threadIdx.x >> 5;
    const int r0 = blockIdx.y * 32;
    const int c0 = blockIdx.x * 32;
#pragma unroll
    for (int j = 0; j < 32; j += 8)
        t[ty + j][tx] = in[(size_t)(r0 + ty + j) * ldin + c0 + tx];
    __syncthreads();
#pragma unroll
    for (int j = 0; j < 32; j += 8) {
        float x = t[tx][ty + j];
        __hip_bfloat16 h = f2bf(x);
        size_t o = (size_t)(c0 + ty + j) * ldout + r0 + tx;
        ohi[o] = h;
        if (olo) olo[o] = f2bf(x - bf2f(h));
    }
}

// fp8 byte transpose (V part of QKVf8 -> VTf8)
__global__ __launch_bounds__(256)
void transpose_f8(const uint8_t* __restrict__ in, int ldin,
                  uint8_t* __restrict__ out, int ldout)
{
    __shared__ uint8_t t[32][33];
    const int tx = threadIdx.x & 31;
    const int ty = threadIdx.x >> 5;
    const int r0 = blockIdx.y * 32;
    const int c0 = blockIdx.x * 32;
#pragma unroll
    for (int j = 0; j < 32; j += 8)
        t[ty + j][tx] = in[(size_t)(r0 + ty + j) * ldin + c0 + tx];
    __syncthreads();
#pragma unroll
    for (int j = 0; j < 32; j += 8)
        out[(size_t)(c0 + ty + j) * ldout + r0 + tx] = t[tx][ty + j];
}

__global__ __launch_bounds__(256)
void cvt_split(const float* __restrict__ in, __hip_bfloat16* __restrict__ hi,
               __hip_bfloat16* __restrict__ lo)
{
    const int i = (blockIdx.x * 256 + threadIdx.x) * 4;
    f32x4 v = *(const f32x4*)(in + i);
#pragma unroll
    for (int k = 0; k < 4; ++k) {
        __hip_bfloat16 h = f2bf(v[k]);
        hi[i + k] = h;
        lo[i + k] = f2bf(v[k] - bf2f(h));
    }
}

// ---------------------------------------------------------------------------
// head tail: r = H2 @ Wh + bh (fp32; hi + optional lo), NIG transforms, opt G.
// ---------------------------------------------------------------------------
__global__ __launch_bounds__(256)
void head_tail(const __hip_bfloat16* __restrict__ H2hi, const __hip_bfloat16* __restrict__ H2lo,
               const float* __restrict__ Wh, const float* __restrict__ bh,
               const float* __restrict__ gamp,
               float* __restrict__ outBase, float* __restrict__ Gout)
{
    __shared__ float sa[64], sb[64];
    const int tid = threadIdx.x;
    const int rl  = tid >> 2;
    const int c   = tid & 3;
    const int row = blockIdx.x * 64 + rl;
    const __hip_bfloat16* hh = H2hi + (size_t)row * DH2;
    const __hip_bfloat16* hl = H2lo ? H2lo + (size_t)row * DH2 : nullptr;
    float acc = bh[c];
    if (hl) {
        for (int k = 0; k < DH2; ++k)
            acc = fmaf(bf2f(hh[k]) + bf2f(hl[k]), Wh[k * 4 + c], acc);
    } else {
        for (int k = 0; k < DH2; ++k)
            acc = fmaf(bf2f(hh[k]), Wh[k * 4 + c], acc);
    }
    float sp = softplus_f(acc);
    if (c == 0) {
        outBase[row] = acc;                        // mu
    } else if (c == 1) {
        outBase[NT + row] = sp + 1e-6f;            // v
    } else if (c == 2) {
        float a0 = (sp + 1.0f) + 1e-6f;            // match ref assoc order
        outBase[2 * NT + row] = a0;
        if (Gout) sa[rl] = a0 - 1.0f;
    } else {
        float b0 = sp + 1e-6f;
        outBase[3 * NT + row] = b0;
        if (Gout) sb[rl] = b0;
    }
    if (Gout != nullptr) {
        __syncthreads();
        if (c == 0) {
            float u   = sb[rl] / fmaxf(sa[rl], 1e-8f);
            float sig = 1.0f / (1.0f + expf(-u));
            Gout[row] = 1.0f - gamp[0] * sig;
        }
    }
}

// ---------------------------------------------------------------------------
extern "C" void kernel_launch(void* const* d_in, const int* in_sizes, int n_in,
                              void* d_out, int out_size, void* d_ws, size_t ws_size,
                              hipStream_t stream)
{
    (void)in_sizes; (void)n_in; (void)out_size; (void)ws_size;
    const float* X   = (const float*)d_in[0];
    const float* Wq  = (const float*)d_in[1];
    const float* Wk  = (const float*)d_in[2];
    const float* Wg  = (const float*)d_in[3];
    const float* bg  = (const float*)d_in[4];
    const float* gam = (const float*)d_in[5];
    const float* iW1 = (const float*)d_in[6];
    const float* ib1 = (const float*)d_in[7];
    const float* iW2 = (const float*)d_in[8];
    const float* ib2 = (const float*)d_in[9];
    const float* iWh = (const float*)d_in[10];
    const float* ibh = (const float*)d_in[11];
    const float* fW1 = (const float*)d_in[12];
    const float* fb1 = (const float*)d_in[13];
    const float* fW2 = (const float*)d_in[14];
    const float* fb2 = (const float*)d_in[15];
    const float* fWh = (const float*)d_in[16];
    const float* fbh = (const float*)d_in[17];
    float* out = (float*)d_out;

    char* cur = (char*)d_ws;
    auto alloc = [&](size_t bytes) -> char* {
        char* p = cur;
        cur += (bytes + 255) & ~(size_t)255;
        return p;
    };
    typedef __hip_bfloat16 bf;

    // Region A (64 MB): full Wp fp8 (8192x8192) aliased over buffers that are
    // dead during the attention phase (Xhi/Xlo/H1*/H2*).
    char* regA = alloc((size_t)NT * NT);
    uint8_t* Wp = (uint8_t*)regA;
    bf* Xhi  = (bf*)(regA);
    bf* Xlo  = (bf*)(regA + (size_t)NT * DD * 2);
    bf* H1hi = (bf*)(regA + (size_t)NT * DD * 4);
    bf* H1lo = (bf*)(regA + (size_t)NT * DD * 4 + (size_t)NT * DH1 * 2);
    bf* H2hi = (bf*)(regA + (size_t)NT * DD * 4 + (size_t)NT * DH1 * 4);
    bf* H2lo = (bf*)(regA + (size_t)NT * DD * 4 + (size_t)NT * DH1 * 4 + (size_t)NT * DH2 * 2);

    bf* WqkvT  = (bf*)alloc((size_t)3 * DD * DD * 2);
    bf* iW1hiT = (bf*)alloc((size_t)DH1 * DD * 2);
    bf* iW1loT = (bf*)alloc((size_t)DH1 * DD * 2);
    bf* iW2hiT = (bf*)alloc((size_t)DH2 * DH1 * 2);
    bf* iW2loT = (bf*)alloc((size_t)DH2 * DH1 * 2);
    bf* fW1hiT = (bf*)alloc((size_t)DH1 * DD * 2);
    bf* fW2hiT = (bf*)alloc((size_t)DH2 * DH1 * 2);
    uint8_t* QKVf8 = (uint8_t*)alloc((size_t)NT * 3 * DD);   // 8192 x 2304 fp8
    uint8_t* VTf8  = (uint8_t*)alloc((size_t)DD * NT);       // 768 x 8192 fp8
    float* G    = (float*)alloc((size_t)NT * 4);
    float* E    = (float*)alloc((size_t)NT * 4);
    float* T    = (float*)alloc((size_t)NT * 4);
    bf* Yhi    = (bf*)alloc((size_t)NT * DD * 2);

    const dim3 blk(256);

    // 1. converts / transposes
    cvt_split<<<dim3(NT * DD / 1024), blk, 0, stream>>>(X, Xhi, Xlo);
    transpose_f2b<<<dim3(DD / 32, DD / 32), blk, 0, stream>>>(Wq, DD, WqkvT, nullptr, DD);
    transpose_f2b<<<dim3(DD / 32, DD / 32), blk, 0, stream>>>(Wk, DD, WqkvT + (size_t)DD * DD, nullptr, DD);
    transpose_f2b<<<dim3(DD / 32, DD / 32), blk, 0, stream>>>(Wg, DD, WqkvT + (size_t)2 * DD * DD, nullptr, DD);
    transpose_f2b<<<dim3(DH1 / 32, DD / 32), blk, 0, stream>>>(iW1, DH1, iW1hiT, iW1loT, DD);
    transpose_f2b<<<dim3(DH2 / 32, DH1 / 32), blk, 0, stream>>>(iW2, DH2, iW2hiT, iW2loT, DH1);
    transpose_f2b<<<dim3(DH1 / 32, DD / 32), blk, 0, stream>>>(fW1, DH1, fW1hiT, nullptr, DD);
    transpose_f2b<<<dim3(DH2 / 32, DH1 / 32), blk, 0, stream>>>(fW2, DH2, fW2hiT, nullptr, DH1);

    // 2. head 1 (split-bf16 — G-cliff precision)
    gemm_bt<1, true, 64, 64><<<dim3(DH1 / 64, NT / 64), blk, 0, stream>>>(
        Xhi, Xlo, DD, iW1hiT, iW1loT, DD, H1hi, H1lo, nullptr, DH1, ib1, DD);
    gemm_bt<1, true, 64, 64><<<dim3(DH2 / 64, NT / 64), blk, 0, stream>>>(
        H1hi, H1lo, DH1, iW2hiT, iW2loT, DH1, H2hi, H2lo, nullptr, DH2, ib2, DH1);
    head_tail<<<dim3(NT / 64), blk, 0, stream>>>(H2hi, H2lo, iWh, ibh, gam, out, G);

    // 3. QKV projection -> fp8 directly (last reader of Xhi)
    gemm_bt<0, false, 128, 128><<<dim3(3 * DD / 128, NT / 128), blk, 0, stream>>>(
        Xhi, nullptr, DD, WqkvT, nullptr, DD, nullptr, nullptr, QKVf8, 3 * DD,
        nullptr, DD);
    transpose_f8<<<dim3(DD / 32, NT / 32), blk, 0, stream>>>(QKVf8 + 2 * DD, 3 * DD, VTf8, NT);

    hipMemsetAsync(E, 0, (size_t)NT * 4, stream);
    hipMemsetAsync(T, 0, (size_t)NT * 4, stream);

    // 4a. scores in two N=4096 dispatches (K panel 3.1 MB stays L2-resident
    //     per XCD). Both write the full Wp; Wp clobbers region A (dead bufs).
    for (int p = 0; p < 2; ++p) {
        const uint8_t* Kp = QKVf8 + (size_t)p * SPAN * (3 * DD) + DD;
        gemm_f8<2, 128, 128><<<dim3(SPAN / 128, NT / 128), blk, 0, stream>>>(
            QKVf8, 3 * DD, Kp, 3 * DD, Wp + (size_t)p * SPAN, NT,
            G + p * SPAN, E, T, nullptr, nullptr, nullptr, nullptr, nullptr, nullptr, DD);
    }

    // 4b. PV with fused Y epilogue, 64x64 tiles (1536 blocks = 6/CU residency).
    gemm_f8<4, 64, 64><<<dim3(DD / 64, NT / 64), blk, 0, stream>>>(
        Wp, NT, VTf8, NT, nullptr, DD,
        nullptr, nullptr, nullptr, X, bg, G, E, T, Yhi, NT);

    // 5. head 2 — plain bf16 (smooth outputs, ample threshold margin)
    gemm_bt<1, false, 64, 64><<<dim3(DH1 / 64, NT / 64), blk, 0, stream>>>(
        Yhi, nullptr, DD, fW1hiT, nullptr, DD, H1hi, nullptr, nullptr, DH1, fb1, DD);
    gemm_bt<1, false, 64, 64><<<dim3(DH2 / 64, NT / 64), blk, 0, stream>>>(
        H1hi, nullptr, DH1, fW2hiT, nullptr, DH1, H2hi, nullptr, nullptr, DH2, fb2, DH1);
    head_tail<<<dim3(NT / 64), blk, 0, stream>>>(H2hi, nullptr, fWh, fbh, gam, out + 4 * NT, nullptr);
}

// Round 11
// 539.458 us; speedup vs baseline: 1.3055x; 1.3055x over previous
//
#include <hip/hip_runtime.h>
#include <hip/hip_bf16.h>
#include <hip/hip_fp8.h>
#include <math.h>
#include <stdint.h>
#include <stddef.h>

// ---------------------------------------------------------------------------
// MetaEvidentialGSL: N=8192, D=768, H1=512, H2=256
// R2: XOR swizzle -> 0 conflicts. R4: dbuf + raw vmcnt barrier. R5: XCD
// remap. R6: head2 plain bf16. R7: fp8 attention. R8: fused-Y PV.
// R9: scores 2xN=4096 (L2-resident B), PV 64x64 (6 blk/CU). 549 us.
// R10 FAILED (A direct->VGPR: half-line fetches doubled HBM traffic +
//     exposed global latency per iter). Reverted.
// R11: R9 fp8 path restored verbatim + head_tail rewritten as one wave/row
//     (coalesced Wh reads, f32x4 partials, butterfly shuffle-reduce) --
//     was 4 thr/row x 256 sequential scalar iters.
// ---------------------------------------------------------------------------

#define NT    8192
#define DD    768
#define DH1   512
#define DH2   256
#define SPAN  4096   // scores N-split

typedef __attribute__((ext_vector_type(8))) short  short8;
typedef __attribute__((ext_vector_type(4))) short  short4v;
typedef __attribute__((ext_vector_type(4))) float  f32x4;
typedef __attribute__((ext_vector_type(2))) long   longx2;

#define MFMA16(a, b, c) __builtin_amdgcn_mfma_f32_16x16x32_bf16((a), (b), (c), 0, 0, 0)
#define MFMAF8(a, b, c) __builtin_amdgcn_mfma_f32_16x16x32_fp8_fp8((a), (b), (c), 0, 0, 0)

__device__ __forceinline__ float bf2f(__hip_bfloat16 x) { return __bfloat162float(x); }
__device__ __forceinline__ __hip_bfloat16 f2bf(float x) { return __float2bfloat16(x); }
__device__ __forceinline__ uint8_t f2fp8(float x) { return __hip_fp8_e4m3(x).__x; }
__device__ __forceinline__ float bfbits2f(short u) {
    union { unsigned int i; float f; } c; c.i = ((unsigned int)(unsigned short)u) << 16; return c.f;
}

__device__ __forceinline__ float gelu_f(float x) {
    return 0.5f * x * (1.0f + erff(x * 0.7071067811865476f));
}
__device__ __forceinline__ float softplus_f(float x) {
    return (x > 20.0f) ? x : log1pf(expf(x));
}

// async 16B/lane global->LDS. LDS dest must be wave-uniform base + lane*16.
__device__ __forceinline__ void gload16(const void* g, void* l) {
    __builtin_amdgcn_global_load_lds(
        (const __attribute__((address_space(1))) void*)g,
        (__attribute__((address_space(3))) void*)l, 16, 0, 0);
}

// wait until <=N vm ops outstanding, then barrier.
template <int N>
__device__ __forceinline__ void wait_barrier() {
    asm volatile("s_waitcnt vmcnt(%0)\n\ts_barrier" :: "i"(N) : "memory");
}
__device__ __forceinline__ void plain_barrier() {
    asm volatile("s_barrier" ::: "memory");
}

// XCD-aware remap: linear workgroup id round-robins across 8 XCDs (id % 8).
__device__ __forceinline__ void xcd_remap(int& bx, int& by) {
    const int nbx = gridDim.x, nby = gridDim.y;
    if ((nby & 7) == 0) {
        const int lin = by * nbx + bx;
        const int x   = lin & 7;
        const int s   = lin >> 3;
        bx = s % nbx;
        by = x + 8 * (s / nbx);
    }
}

// ---------------------------------------------------------------------------
// bf16 GEMM (heads + QKV): C(MxN) = A @ Bt^T. BK=32, double-buffered.
// EPI: 0 = store bf16 (obf_hi) and/or fp8 (of8); 1 = bias+gelu -> bf16 (+lo)
// ---------------------------------------------------------------------------
template <int EPI, bool SPLIT, int TM, int TN>
__global__ __launch_bounds__(256)
void gemm_bt(const __hip_bfloat16* __restrict__ Ahi, const __hip_bfloat16* __restrict__ Alo, int lda,
             const __hip_bfloat16* __restrict__ Bhi, const __hip_bfloat16* __restrict__ Blo, int ldb,
             __hip_bfloat16* __restrict__ obf_hi, __hip_bfloat16* __restrict__ obf_lo,
             uint8_t* __restrict__ of8, int ldc,
             const float* __restrict__ bias, int K)
{
    constexpr int NB  = SPLIT ? 2 : 1;
    constexpr int WRM = (TM == 128 && TN == 128) ? 2 : (TM == 128 ? 4 : 2);
    constexpr int WCN = 4 / WRM;
    constexpr int WTM = TM / WRM;
    constexpr int WTN = TN / WCN;
    constexpr int MI  = WTM / 16;
    constexpr int NI  = WTN / 16;
    constexpr int PA  = TM / 64;
    constexpr int PB  = TN / 64;
    constexpr int LPI = (PA + PB) * NB;

    __shared__ __align__(16) __hip_bfloat16 As[NB][2][TM * 32];
    __shared__ __align__(16) __hip_bfloat16 Bs[NB][2][TN * 32];

    const int tid  = threadIdx.x;
    const int wave = tid >> 6;
    const int lane = tid & 63;
    int bx = blockIdx.x, by = blockIdx.y;
    xcd_remap(bx, by);
    const int tm = by * TM;
    const int tn = bx * TN;

    const int srow  = tid >> 2;
    const int sgcol = ((tid & 3) ^ ((srow >> 1) & 3)) * 8;
    const int lofs  = srow * 32 + (tid & 3) * 8;

    size_t aoffs[PA], boffs[PB];
#pragma unroll
    for (int p = 0; p < PA; ++p) aoffs[p] = (size_t)(tm + p * 64 + srow) * lda + sgcol;
#pragma unroll
    for (int p = 0; p < PB; ++p) boffs[p] = (size_t)(tn + p * 64 + srow) * ldb + sgcol;

    auto stage = [&](int k0, int buf) {
#pragma unroll
        for (int p = 0; p < PA; ++p)
            gload16(Ahi + aoffs[p] + k0, &As[0][buf][p * 2048 + lofs]);
#pragma unroll
        for (int p = 0; p < PB; ++p)
            gload16(Bhi + boffs[p] + k0, &Bs[0][buf][p * 2048 + lofs]);
        if constexpr (SPLIT) {
#pragma unroll
            for (int p = 0; p < PA; ++p)
                gload16(Alo + aoffs[p] + k0, &As[1][buf][p * 2048 + lofs]);
#pragma unroll
            for (int p = 0; p < PB; ++p)
                gload16(Blo + boffs[p] + k0, &Bs[1][buf][p * 2048 + lofs]);
        }
    };

    f32x4 acc[MI][NI];
#pragma unroll
    for (int i = 0; i < MI; ++i)
#pragma unroll
        for (int j = 0; j < NI; ++j) {
            f32x4 z = {0.0f, 0.0f, 0.0f, 0.0f};
            acc[i][j] = z;
        }

    const int wm   = (wave / WCN) * WTM;
    const int wn   = (wave % WCN) * WTN;
    const int l16  = lane & 15;
    const int quad = lane >> 4;
    const int rchunk = (quad ^ ((l16 >> 1) & 3)) * 8;
    const int arow0  = (wm + l16) * 32 + rchunk;
    const int brow0  = (wn + l16) * 32 + rchunk;

    const int nIter = K >> 5;
    stage(0, 0);
    for (int k = 0; k < nIter; ++k) {
        const int cb = k & 1;
        if (k + 1 < nIter) {
            stage((k + 1) << 5, cb ^ 1);
            wait_barrier<LPI>();
        } else {
            wait_barrier<0>();
        }

        short8 ah[MI], bh[NI];
#pragma unroll
        for (int i = 0; i < MI; ++i) ah[i] = *(const short8*)&As[0][cb][arow0 + i * 512];
#pragma unroll
        for (int j = 0; j < NI; ++j) bh[j] = *(const short8*)&Bs[0][cb][brow0 + j * 512];
        if constexpr (SPLIT) {
            short8 al[MI], bl[NI];
#pragma unroll
            for (int i = 0; i < MI; ++i) al[i] = *(const short8*)&As[1][cb][arow0 + i * 512];
#pragma unroll
            for (int j = 0; j < NI; ++j) bl[j] = *(const short8*)&Bs[1][cb][brow0 + j * 512];
#pragma unroll
            for (int mi = 0; mi < MI; ++mi)
#pragma unroll
                for (int ni = 0; ni < NI; ++ni) {
                    acc[mi][ni] = MFMA16(ah[mi], bh[ni], acc[mi][ni]);
                    acc[mi][ni] = MFMA16(ah[mi], bl[ni], acc[mi][ni]);
                    acc[mi][ni] = MFMA16(al[mi], bh[ni], acc[mi][ni]);
                }
        } else {
#pragma unroll
            for (int mi = 0; mi < MI; ++mi)
#pragma unroll
                for (int ni = 0; ni < NI; ++ni)
                    acc[mi][ni] = MFMA16(ah[mi], bh[ni], acc[mi][ni]);
        }
        plain_barrier();
    }

    // C/D layout: col = lane&15, row = (lane>>4)*4 + reg  [verified m89/m91]
    const int rbase = tm + wm + quad * 4;
    const int cbase = tn + wn + l16;

    if constexpr (EPI == 0) {
#pragma unroll
        for (int mi = 0; mi < MI; ++mi)
#pragma unroll
            for (int ni = 0; ni < NI; ++ni) {
                f32x4 v = acc[mi][ni];
                const int col = cbase + ni * 16;
#pragma unroll
                for (int r = 0; r < 4; ++r) {
                    size_t idx = (size_t)(rbase + mi * 16 + r) * ldc + col;
                    if (obf_hi) obf_hi[idx] = f2bf(v[r]);
                    if (of8)    of8[idx]    = f2fp8(v[r]);
                }
            }
    } else {  // EPI == 1
#pragma unroll
        for (int mi = 0; mi < MI; ++mi)
#pragma unroll
            for (int ni = 0; ni < NI; ++ni) {
                f32x4 v = acc[mi][ni];
                const int col = cbase + ni * 16;
                const float b = bias[col];
#pragma unroll
                for (int r = 0; r < 4; ++r) {
                    float g = gelu_f(v[r] + b);
                    __hip_bfloat16 h = f2bf(g);
                    size_t idx = (size_t)(rbase + mi * 16 + r) * ldc + col;
                    obf_hi[idx] = h;
                    if (obf_lo) obf_lo[idx] = f2bf(g - bf2f(h));
                }
            }
    }
}

// ---------------------------------------------------------------------------
// fp8 GEMM (attention): C(MxN) = A(MxK) @ Bt(NxK)^T, fp8 e4m3 inputs.
// BK=64, double-buffered LDS for A and B, byte-level XOR swizzle (0 conflicts).
// EPI: 2 = w=exp(acc/sqrt(D))*G[col] -> fp8, atomic rowsum E (exp) / T (w)
//      4 = fused Y epilogue: Y = X + gelu(alpha*acc + bg),
//          alpha = G/(E*max(G*T/E,1e-8))   (exact reference clamp semantics)
// ---------------------------------------------------------------------------
template <int EPI, int TM, int TN>
__global__ __launch_bounds__(256)
void gemm_f8(const uint8_t* __restrict__ A, int lda,
             const uint8_t* __restrict__ B, int ldb,
             uint8_t* __restrict__ of8, int ldc,
             const float* __restrict__ Gv, float* __restrict__ Esum,
             float* __restrict__ Tsum,
             const float* __restrict__ Xf, const float* __restrict__ bg2,
             const float* __restrict__ Grow, const float* __restrict__ Erow,
             const float* __restrict__ Trow,
             __hip_bfloat16* __restrict__ Yout, int K)
{
    constexpr int WRM = (TM == 128 && TN == 128) ? 2 : (TM == 128 ? 4 : 2);
    constexpr int WCN = 4 / WRM;
    constexpr int WTM = TM / WRM;
    constexpr int WTN = TN / WCN;
    constexpr int MI  = WTM / 16;
    constexpr int NI  = WTN / 16;
    constexpr int PA  = TM / 64;
    constexpr int PB  = TN / 64;
    constexpr int LPI = PA + PB;

    __shared__ __align__(16) uint8_t As[2][TM * 64];
    __shared__ __align__(16) uint8_t Bs[2][TN * 64];

    const int tid  = threadIdx.x;
    const int wave = tid >> 6;
    const int lane = tid & 63;
    int bx = blockIdx.x, by = blockIdx.y;
    xcd_remap(bx, by);
    const int tm = by * TM;
    const int tn = bx * TN;

    const int srow  = tid >> 2;
    const int sgcol = ((tid & 3) ^ ((srow >> 1) & 3)) * 16;   // byte col
    const int lofs  = tid * 16;

    size_t aoffs[PA], boffs[PB];
#pragma unroll
    for (int p = 0; p < PA; ++p) aoffs[p] = (size_t)(tm + p * 64 + srow) * lda + sgcol;
#pragma unroll
    for (int p = 0; p < PB; ++p) boffs[p] = (size_t)(tn + p * 64 + srow) * ldb + sgcol;

    auto stage = [&](int k0, int buf) {
#pragma unroll
        for (int p = 0; p < PA; ++p)
            gload16(A + aoffs[p] + k0, &As[buf][p * 4096 + lofs]);
#pragma unroll
        for (int p = 0; p < PB; ++p)
            gload16(B + boffs[p] + k0, &Bs[buf][p * 4096 + lofs]);
    };

    f32x4 acc[MI][NI];
#pragma unroll
    for (int i = 0; i < MI; ++i)
#pragma unroll
        for (int j = 0; j < NI; ++j) {
            f32x4 z = {0.0f, 0.0f, 0.0f, 0.0f};
            acc[i][j] = z;
        }

    const int wm   = (wave / WCN) * WTM;
    const int wn   = (wave % WCN) * WTN;
    const int l16  = lane & 15;
    const int quad = lane >> 4;
    const int rchunk = (quad ^ ((l16 >> 1) & 3)) * 16;
    const int arow0  = (wm + l16) * 64 + rchunk;
    const int brow0  = (wn + l16) * 64 + rchunk;

    const int nIter = K >> 6;
    stage(0, 0);
    for (int k = 0; k < nIter; ++k) {
        const int cb = k & 1;
        if (k + 1 < nIter) {
            stage((k + 1) << 6, cb ^ 1);
            wait_barrier<LPI>();
        } else {
            wait_barrier<0>();
        }

        longx2 a[MI], b[NI];
#pragma unroll
        for (int i = 0; i < MI; ++i) a[i] = *(const longx2*)&As[cb][arow0 + i * 1024];
#pragma unroll
        for (int j = 0; j < NI; ++j) b[j] = *(const longx2*)&Bs[cb][brow0 + j * 1024];
#pragma unroll
        for (int mi = 0; mi < MI; ++mi)
#pragma unroll
            for (int ni = 0; ni < NI; ++ni) {
                acc[mi][ni] = MFMAF8(a[mi][0], b[ni][0], acc[mi][ni]);
                acc[mi][ni] = MFMAF8(a[mi][1], b[ni][1], acc[mi][ni]);
            }
        plain_barrier();
    }

    const int rbase = tm + wm + quad * 4;
    const int cbase = tn + wn + l16;

    if constexpr (EPI == 2) {
        const float SCL = 0.03608439182435161f;   // 1/sqrt(768)
#pragma unroll
        for (int mi = 0; mi < MI; ++mi) {
            float sE[4] = {0.f, 0.f, 0.f, 0.f};
            float sT[4] = {0.f, 0.f, 0.f, 0.f};
#pragma unroll
            for (int ni = 0; ni < NI; ++ni) {
                f32x4 v = acc[mi][ni];
                const int col = cbase + ni * 16;
                const float g = Gv[col];
#pragma unroll
                for (int r = 0; r < 4; ++r) {
                    float we = __expf(v[r] * SCL);
                    float w  = we * g;
                    of8[(size_t)(rbase + mi * 16 + r) * ldc + col] = f2fp8(w);
                    sE[r] += we;
                    sT[r] += w;
                }
            }
#pragma unroll
            for (int st = 1; st < 16; st <<= 1)
#pragma unroll
                for (int r = 0; r < 4; ++r) {
                    sE[r] += __shfl_xor(sE[r], st);
                    sT[r] += __shfl_xor(sT[r], st);
                }
            if (l16 == 0) {
#pragma unroll
                for (int r = 0; r < 4; ++r) {
                    atomicAdd(&Esum[rbase + mi * 16 + r], sE[r]);
                    atomicAdd(&Tsum[rbase + mi * 16 + r], sT[r]);
                }
            }
        }
    } else {  // EPI == 4: fused Y = X + gelu(alpha*acc + bg)
#pragma unroll
        for (int mi = 0; mi < MI; ++mi) {
#pragma unroll
            for (int r = 0; r < 4; ++r) {
                const int row = rbase + mi * 16 + r;
                const float g = Grow[row], e = Erow[row], t = Trow[row];
                const float denom = fmaxf(g * t / e, 1e-8f);
                const float alpha = g / (e * denom);
#pragma unroll
                for (int ni = 0; ni < NI; ++ni) {
                    const int col = cbase + ni * 16;
                    const float m = alpha * acc[mi][ni][r];
                    const size_t idx = (size_t)row * ldc + col;
                    Yout[idx] = f2bf(Xf[idx] + gelu_f(m + bg2[col]));
                }
            }
        }
    }
}

// ---------------------------------------------------------------------------
__global__ __launch_bounds__(256)
void transpose_f2b(const float* __restrict__ in, int ldin,
                   __hip_bfloat16* __restrict__ ohi, __hip_bfloat16* __restrict__ olo, int ldout)
{
    __shared__ float t[32][33];
    const int tx = threadIdx.x & 31;
    const int ty = threadIdx.x >> 5;
    const int r0 = blockIdx.y * 32;
    const int c0 = blockIdx.x * 32;
#pragma unroll
    for (int j = 0; j < 32; j += 8)
        t[ty + j][tx] = in[(size_t)(r0 + ty + j) * ldin + c0 + tx];
    __syncthreads();
#pragma unroll
    for (int j = 0; j < 32; j += 8) {
        float x = t[tx][ty + j];
        __hip_bfloat16 h = f2bf(x);
        size_t o = (size_t)(c0 + ty + j) * ldout + r0 + tx;
        ohi[o] = h;
        if (olo) olo[o] = f2bf(x - bf2f(h));
    }
}

// fp8 byte transpose (V part of QKVf8 -> VTf8)
__global__ __launch_bounds__(256)
void transpose_f8(const uint8_t* __restrict__ in, int ldin,
                  uint8_t* __restrict__ out, int ldout)
{
    __shared__ uint8_t t[32][33];
    const int tx = threadIdx.x & 31;
    const int ty = threadIdx.x >> 5;
    const int r0 = blockIdx.y * 32;
    const int c0 = blockIdx.x * 32;
#pragma unroll
    for (int j = 0; j < 32; j += 8)
        t[ty + j][tx] = in[(size_t)(r0 + ty + j) * ldin + c0 + tx];
    __syncthreads();
#pragma unroll
    for (int j = 0; j < 32; j += 8)
        out[(size_t)(c0 + ty + j) * ldout + r0 + tx] = t[tx][ty + j];
}

__global__ __launch_bounds__(256)
void cvt_split(const float* __restrict__ in, __hip_bfloat16* __restrict__ hi,
               __hip_bfloat16* __restrict__ lo)
{
    const int i = (blockIdx.x * 256 + threadIdx.x) * 4;
    f32x4 v = *(const f32x4*)(in + i);
#pragma unroll
    for (int k = 0; k < 4; ++k) {
        __hip_bfloat16 h = f2bf(v[k]);
        hi[i + k] = h;
        lo[i + k] = f2bf(v[k] - bf2f(h));
    }
}

// ---------------------------------------------------------------------------
// head tail: one wave per row. Lane covers k = lane*4..lane*4+3 (K=256);
// coalesced 64 B Wh reads; f32x4 partials; butterfly shuffle-reduce; lane 0
// applies the NIG transforms (exact reference fp32 rounding/clamps) + G.
// ---------------------------------------------------------------------------
__global__ __launch_bounds__(256)
void head_tail(const __hip_bfloat16* __restrict__ H2hi, const __hip_bfloat16* __restrict__ H2lo,
               const float* __restrict__ Wh, const float* __restrict__ bh,
               const float* __restrict__ gamp,
               float* __restrict__ outBase, float* __restrict__ Gout)
{
    const int wave = threadIdx.x >> 6;
    const int lane = threadIdx.x & 63;
    const int row  = blockIdx.x * 4 + wave;
    const int k0   = lane * 4;

    short4v ph = *(const short4v*)(H2hi + (size_t)row * DH2 + k0);
    float hv[4];
#pragma unroll
    for (int j = 0; j < 4; ++j) hv[j] = bfbits2f(ph[j]);
    if (H2lo) {
        short4v pl = *(const short4v*)(H2lo + (size_t)row * DH2 + k0);
#pragma unroll
        for (int j = 0; j < 4; ++j) hv[j] += bfbits2f(pl[j]);
    }
    const f32x4* wrow = (const f32x4*)(Wh + (size_t)k0 * 4);   // rows k0..k0+3, 4 cols
    f32x4 s = {0.0f, 0.0f, 0.0f, 0.0f};
#pragma unroll
    for (int j = 0; j < 4; ++j) {
        f32x4 w = wrow[j];
#pragma unroll
        for (int c = 0; c < 4; ++c) s[c] = fmaf(hv[j], w[c], s[c]);
    }
#pragma unroll
    for (int st = 1; st < 64; st <<= 1)
#pragma unroll
        for (int c = 0; c < 4; ++c) s[c] += __shfl_xor(s[c], st);

    if (lane == 0) {
        const float r0 = s[0] + bh[0];
        const float r1 = s[1] + bh[1];
        const float r2 = s[2] + bh[2];
        const float r3 = s[3] + bh[3];
        outBase[row] = r0;                                   // mu
        outBase[NT + row] = softplus_f(r1) + 1e-6f;          // v
        float a0 = (softplus_f(r2) + 1.0f) + 1e-6f;          // ref assoc order
        outBase[2 * NT + row] = a0;
        float b0 = softplus_f(r3) + 1e-6f;
        outBase[3 * NT + row] = b0;
        if (Gout) {
            float u   = b0 / fmaxf(a0 - 1.0f, 1e-8f);
            float sig = 1.0f / (1.0f + expf(-u));            // fp32 cliff = ref
            Gout[row] = 1.0f - gamp[0] * sig;
        }
    }
}

// ---------------------------------------------------------------------------
extern "C" void kernel_launch(void* const* d_in, const int* in_sizes, int n_in,
                              void* d_out, int out_size, void* d_ws, size_t ws_size,
                              hipStream_t stream)
{
    (void)in_sizes; (void)n_in; (void)out_size; (void)ws_size;
    const float* X   = (const float*)d_in[0];
    const float* Wq  = (const float*)d_in[1];
    const float* Wk  = (const float*)d_in[2];
    const float* Wg  = (const float*)d_in[3];
    const float* bg  = (const float*)d_in[4];
    const float* gam = (const float*)d_in[5];
    const float* iW1 = (const float*)d_in[6];
    const float* ib1 = (const float*)d_in[7];
    const float* iW2 = (const float*)d_in[8];
    const float* ib2 = (const float*)d_in[9];
    const float* iWh = (const float*)d_in[10];
    const float* ibh = (const float*)d_in[11];
    const float* fW1 = (const float*)d_in[12];
    const float* fb1 = (const float*)d_in[13];
    const float* fW2 = (const float*)d_in[14];
    const float* fb2 = (const float*)d_in[15];
    const float* fWh = (const float*)d_in[16];
    const float* fbh = (const float*)d_in[17];
    float* out = (float*)d_out;

    char* cur = (char*)d_ws;
    auto alloc = [&](size_t bytes) -> char* {
        char* p = cur;
        cur += (bytes + 255) & ~(size_t)255;
        return p;
    };
    typedef __hip_bfloat16 bf;

    // Region A (64 MB): full Wp fp8 (8192x8192) aliased over buffers that are
    // dead during the attention phase (Xhi/Xlo/H1*/H2*).
    char* regA = alloc((size_t)NT * NT);
    uint8_t* Wp = (uint8_t*)regA;
    bf* Xhi  = (bf*)(regA);
    bf* Xlo  = (bf*)(regA + (size_t)NT * DD * 2);
    bf* H1hi = (bf*)(regA + (size_t)NT * DD * 4);
    bf* H1lo = (bf*)(regA + (size_t)NT * DD * 4 + (size_t)NT * DH1 * 2);
    bf* H2hi = (bf*)(regA + (size_t)NT * DD * 4 + (size_t)NT * DH1 * 4);
    bf* H2lo = (bf*)(regA + (size_t)NT * DD * 4 + (size_t)NT * DH1 * 4 + (size_t)NT * DH2 * 2);

    bf* WqkvT  = (bf*)alloc((size_t)3 * DD * DD * 2);
    bf* iW1hiT = (bf*)alloc((size_t)DH1 * DD * 2);
    bf* iW1loT = (bf*)alloc((size_t)DH1 * DD * 2);
    bf* iW2hiT = (bf*)alloc((size_t)DH2 * DH1 * 2);
    bf* iW2loT = (bf*)alloc((size_t)DH2 * DH1 * 2);
    bf* fW1hiT = (bf*)alloc((size_t)DH1 * DD * 2);
    bf* fW2hiT = (bf*)alloc((size_t)DH2 * DH1 * 2);
    uint8_t* QKVf8 = (uint8_t*)alloc((size_t)NT * 3 * DD);   // 8192 x 2304 fp8
    uint8_t* VTf8  = (uint8_t*)alloc((size_t)DD * NT);       // 768 x 8192 fp8
    float* G    = (float*)alloc((size_t)NT * 4);
    float* E    = (float*)alloc((size_t)NT * 4);
    float* T    = (float*)alloc((size_t)NT * 4);
    bf* Yhi    = (bf*)alloc((size_t)NT * DD * 2);

    const dim3 blk(256);

    // 1. converts / transposes
    cvt_split<<<dim3(NT * DD / 1024), blk, 0, stream>>>(X, Xhi, Xlo);
    transpose_f2b<<<dim3(DD / 32, DD / 32), blk, 0, stream>>>(Wq, DD, WqkvT, nullptr, DD);
    transpose_f2b<<<dim3(DD / 32, DD / 32), blk, 0, stream>>>(Wk, DD, WqkvT + (size_t)DD * DD, nullptr, DD);
    transpose_f2b<<<dim3(DD / 32, DD / 32), blk, 0, stream>>>(Wg, DD, WqkvT + (size_t)2 * DD * DD, nullptr, DD);
    transpose_f2b<<<dim3(DH1 / 32, DD / 32), blk, 0, stream>>>(iW1, DH1, iW1hiT, iW1loT, DD);
    transpose_f2b<<<dim3(DH2 / 32, DH1 / 32), blk, 0, stream>>>(iW2, DH2, iW2hiT, iW2loT, DH1);
    transpose_f2b<<<dim3(DH1 / 32, DD / 32), blk, 0, stream>>>(fW1, DH1, fW1hiT, nullptr, DD);
    transpose_f2b<<<dim3(DH2 / 32, DH1 / 32), blk, 0, stream>>>(fW2, DH2, fW2hiT, nullptr, DH1);

    // 2. head 1 (split-bf16 — G-cliff precision)
    gemm_bt<1, true, 64, 64><<<dim3(DH1 / 64, NT / 64), blk, 0, stream>>>(
        Xhi, Xlo, DD, iW1hiT, iW1loT, DD, H1hi, H1lo, nullptr, DH1, ib1, DD);
    gemm_bt<1, true, 64, 64><<<dim3(DH2 / 64, NT / 64), blk, 0, stream>>>(
        H1hi, H1lo, DH1, iW2hiT, iW2loT, DH1, H2hi, H2lo, nullptr, DH2, ib2, DH1);
    head_tail<<<dim3(NT / 4), blk, 0, stream>>>(H2hi, H2lo, iWh, ibh, gam, out, G);

    // 3. QKV projection -> fp8 directly (last reader of Xhi)
    gemm_bt<0, false, 128, 128><<<dim3(3 * DD / 128, NT / 128), blk, 0, stream>>>(
        Xhi, nullptr, DD, WqkvT, nullptr, DD, nullptr, nullptr, QKVf8, 3 * DD,
        nullptr, DD);
    transpose_f8<<<dim3(DD / 32, NT / 32), blk, 0, stream>>>(QKVf8 + 2 * DD, 3 * DD, VTf8, NT);

    hipMemsetAsync(E, 0, (size_t)NT * 4, stream);
    hipMemsetAsync(T, 0, (size_t)NT * 4, stream);

    // 4a. scores in two N=4096 dispatches (K panel 3.1 MB stays L2-resident
    //     per XCD). Both write the full Wp; Wp clobbers region A (dead bufs).
    for (int p = 0; p < 2; ++p) {
        const uint8_t* Kp = QKVf8 + (size_t)p * SPAN * (3 * DD) + DD;
        gemm_f8<2, 128, 128><<<dim3(SPAN / 128, NT / 128), blk, 0, stream>>>(
            QKVf8, 3 * DD, Kp, 3 * DD, Wp + (size_t)p * SPAN, NT,
            G + p * SPAN, E, T, nullptr, nullptr, nullptr, nullptr, nullptr, nullptr, DD);
    }

    // 4b. PV with fused Y epilogue, 64x64 tiles (1536 blocks = 6/CU residency).
    gemm_f8<4, 64, 64><<<dim3(DD / 64, NT / 64), blk, 0, stream>>>(
        Wp, NT, VTf8, NT, nullptr, DD,
        nullptr, nullptr, nullptr, X, bg, G, E, T, Yhi, NT);

    // 5. head 2 — plain bf16 (smooth outputs, ample threshold margin)
    gemm_bt<1, false, 64, 64><<<dim3(DH1 / 64, NT / 64), blk, 0, stream>>>(
        Yhi, nullptr, DD, fW1hiT, nullptr, DD, H1hi, nullptr, nullptr, DH1, fb1, DD);
    gemm_bt<1, false, 64, 64><<<dim3(DH2 / 64, NT / 64), blk, 0, stream>>>(
        H1hi, nullptr, DH1, fW2hiT, nullptr, DH1, H2hi, nullptr, nullptr, DH2, fb2, DH1);
    head_tail<<<dim3(NT / 4), blk, 0, stream>>>(H2hi, nullptr, fWh, fbh, gam, out + 4 * NT, nullptr);
}